// Round 5
// baseline (301.724 us; speedup 1.0000x reference)
//
#include <hip/hip_runtime.h>
#include <math.h>

// Detector loss: N=65536 samples, G=7 (49 cells), A=3 anchors, C=2 classes.
// bbox_ : (N,15,7,7) predictions, channel 5a+0 = objectness(a), 5a+1..5a+4 = x,y,w,h
// bbox  : (N, 5,7,7) GT,          channel 0 = prob map,        1..4       = x,y,w,h
// cls_  : (N,2) logits; cls : (N,) labels in {1,2}
// out   : scalar fp32
//
// Round-4 (resubmit; prior bench failed on GPU acquisition, no signal):
// fully register-resident. R3 (nt loads) confirmed the cache-debt theory
// (-18 us). Remaining gap vs the 42 us VMEM floor attributed to ~40 DS-pipe
// ops/sample (park + gathers) and their serial waitcnt chains. Since the
// argmax cell m is WAVE-UNIFORM, all scattered gathers are broadcasts ->
// v_readlane from the register-resident sample (VALU pipe, static 2-register
// select per channel). The per-lane prob_loss correction aligns t to the
// objectness registers' natural lanes via ONE uniform-shift shuffle
// ({0,11,22}) instead of gathering p_best. Zero LDS in the loop.

static constexpr int GG  = 49;
static constexpr int PRD = 15 * GG;   // 735 dwords / pred sample
static constexpr int GTD = 5  * GG;   // 245 dwords / gt sample

__global__ void zero_kernel(float* out) { if (threadIdx.x == 0) out[0] = 0.0f; }

__device__ __forceinline__ float rdl(float x, int l) {
    // broadcast read of lane l (runtime-uniform) via v_readlane
    return __int_as_float(__builtin_amdgcn_readlane(__float_as_int(x), l & 63));
}

__global__ __launch_bounds__(256) void loss_kernel(
    const float* __restrict__ pr_all,     // bbox_
    const float* __restrict__ cls_logits, // cls_
    const float* __restrict__ gt_all,     // bbox
    const int*   __restrict__ cls_lbl,    // cls
    float* __restrict__ out, int N)
{
    const int lane  = threadIdx.x & 63;
    const int wslot = threadIdx.x >> 6;
    const int wid   = blockIdx.x * (blockDim.x >> 6) + wslot;
    const int nwaves = gridDim.x * (blockDim.x >> 6);
    const float invG   = 1.0f / 7.0f;
    const float invN   = 1.0f / (float)N;
    const float invN49 = 1.0f / ((float)N * 49.0f);

    float acc = 0.0f;

    for (int n = wid; n < N; n += nwaves) {
        const float* pr = pr_all + (size_t)n * PRD;
        const float* gt = gt_all + (size_t)n * GTD;

        // wave-uniform CE inputs (single-use -> nt), issued with the stream
        const float x0 = __builtin_nontemporal_load(cls_logits + 2 * n);
        const float x1 = __builtin_nontemporal_load(cls_logits + 2 * n + 1);
        const int   cl = __builtin_nontemporal_load(cls_lbl + n);

        // ---- 1) stream the whole sample into registers: 16 nt dword loads ----
        float p[12];
        #pragma unroll
        for (int k = 0; k < 12; ++k) {
            int d = lane + 64 * k;
            if (d > PRD - 1) d = PRD - 1;          // tail clamp (k=11, lanes>30)
            p[k] = __builtin_nontemporal_load(pr + d);
        }
        float g[4];
        #pragma unroll
        for (int k = 0; k < 4; ++k) {
            int d = lane + 64 * k;
            if (d > GTD - 1) d = GTD - 1;          // tail clamp (k=3, lanes>52)
            g[k] = __builtin_nontemporal_load(gt + d);
        }

        // ---- 2) GT prob argmax: 6 max rounds + ballot (min-index tie-break) ----
        const float t = (lane < GG) ? g[0] : -1.0f;  // sentinel loses (probs>=0.01)
        float v = t;
        #pragma unroll
        for (int off = 32; off; off >>= 1) v = fmaxf(v, __shfl_xor(v, off));
        const unsigned long long eq = __ballot(t == v);
        const int m  = __ffsll(eq) - 1;              // wave-uniform, in [0,49)
        const int mi = m / 7, mj = m - mi * 7;
        const float jf = (float)mj, if_ = (float)mi;

        // ---- 3) GT cell box: broadcast readlane from registers ----
        const int d1 = 49 + m, d2 = 98 + m, d3 = 147 + m, d4 = 196 + m;
        const float g1v = (d1 < 64)  ? rdl(g[0], d1) : rdl(g[1], d1);
        const float g2v = (d2 < 128) ? rdl(g[1], d2) : rdl(g[2], d2);
        const float g3v = (d3 < 192) ? rdl(g[2], d3) : rdl(g[3], d3);
        const float g4v = rdl(g[3], d4);             // 196..244 all in g[3]

        const float tx  = (g1v + jf) * invG;
        const float ty  = (g2v + if_) * invG;
        const float tx1 = tx - g3v * 0.5f, tx2 = tx + g3v * 0.5f;
        const float ty1 = ty - g4v * 0.5f, ty2 = ty + g4v * 0.5f;
        const float tarea = (tx2 - tx1) * (ty2 - ty1);

        // ---- 4) IoU argmax over anchors: readlane gathers (static k0/k1) ----
        int best = 0; float bestIoU = -1.0f;
        float px = 0.f, py = 0.f, pw = 0.f, ph = 0.f;
        #pragma unroll
        for (int a = 0; a < 3; a++) {
            float c[4];
            #pragma unroll
            for (int cc = 0; cc < 4; ++cc) {
                const int S  = (5 * a + 1 + cc) * GG;    // compile-time
                const int k0 = S >> 6;                   // compile-time
                const int k1 = (S + GG - 1) >> 6;        // compile-time
                const int d  = S + m;                    // uniform
                c[cc] = (k0 == k1) ? rdl(p[k0], d)
                      : (((d >> 6) == k0) ? rdl(p[k0], d) : rdl(p[k1], d));
            }
            const float ax  = (c[0] + jf) * invG;
            const float ay  = (c[1] + if_) * invG;
            const float ax1 = ax - c[2] * 0.5f, ax2 = ax + c[2] * 0.5f;
            const float ay1 = ay - c[3] * 0.5f, ay2 = ay + c[3] * 0.5f;
            float iw = fminf(ax2, tx2) - fmaxf(ax1, tx1); iw = fmaxf(iw, 0.0f);
            float ih = fminf(ay2, ty2) - fmaxf(ay1, ty1); ih = fmaxf(ih, 0.0f);
            const float inter = iw * ih;
            const float uni   = (ax2 - ax1) * (ay2 - ay1) + tarea - inter;
            const float iou   = inter / (uni + 1e-9f);
            if (iou > bestIoU) { bestIoU = iou; best = a;
                                 px = c[0]; py = c[1]; pw = c[2]; ph = c[3]; }
        }

        // ---- 5) prob_loss on natural register lanes.
        //   objectness dwords: ch0 [0,49) -> p[0] lanes 0..48
        //                      ch1 [245,294) -> p[3] lanes>=53, p[4] lanes<38
        //                      ch2 [490,539) -> p[7] lanes>=42, p[8] lanes<27
        const float l0 = (lane < 49)  ? __logf(1.0f - p[0]) : 0.0f;
        const float l3 = (lane >= 53) ? __logf(1.0f - p[3]) : 0.0f;
        const float l4 = (lane < 38)  ? __logf(1.0f - p[4]) : 0.0f;
        const float l7 = (lane >= 42) ? __logf(1.0f - p[7]) : 0.0f;
        const float l8 = (lane < 27)  ? __logf(1.0f - p[8]) : 0.0f;
        float s = -(l0 + l3 + l4 + l7 + l8);

        // correction: rotate t (cell c at lane c) onto best channel's lanes.
        // ch1: lane l holds cell (l+11)&63; ch2: cell (l+22)&63; ch0: identity.
        const int  rot  = (best == 0) ? 0 : (best == 1) ? 11 : 22;
        const float trot = best ? __shfl(t, (lane + rot) & 63) : t;
        bool  act; float pbin, lb1;
        if (best == 0)      { act = (lane < 49);
                              pbin = p[0]; lb1 = l0; }
        else if (best == 1) { act = (lane >= 53) || (lane < 38);
                              pbin = (lane >= 53) ? p[3] : p[4];
                              lb1  = (lane >= 53) ? l3   : l4; }
        else                { act = (lane >= 42) || (lane < 27);
                              pbin = (lane >= 42) ? p[7] : p[8];
                              lb1  = (lane >= 42) ? l7   : l8; }
        const float lpb = __logf(act ? pbin : 1.0f);
        s -= act ? trot * (lpb - lb1) : 0.0f;
        acc += s * invN49;

        // ---- 6) coord + size: 8 logs packed into ONE v_log_f32 on lanes 0-7.
        //         lanes: 0:px 1:1-px 2:py 3:1-py 4:pw 5:g3 6:ph 7:g4 ----
        const float s0  = (lane < 4) ? ((lane < 2) ? px : py)
                                     : ((lane < 6) ? pw : ph);
        const float s1  = (lane < 4) ? (1.0f - s0)
                                     : ((lane < 6) ? g3v : g4v);
        const float la  = (lane & 1) ? s1 : s0;      // >0 on every lane
        const float Lv  = __logf(la);
        const float Lx  = __shfl_xor(Lv, 1);
        float contrib = 0.0f;
        if (lane < 4) {
            const float w = (lane < 2) ? ((lane & 1) ? 1.0f - g1v : g1v)
                                       : ((lane & 1) ? 1.0f - g2v : g2v);
            contrib = -w * Lv;                        // coord BCE terms
        } else if (lane == 4 || lane == 6) {
            contrib = fabsf(Lv - Lx);                 // size log-L1 terms
        }
        acc += contrib;

        // ---- 7) CE mean on lane 5: lse = mx + log(1 + exp(-|x0-x1|)) ----
        if (lane == 5) {
            const float mx  = fmaxf(x0, x1);
            const float lse = mx + __logf(1.0f + __expf(-fabsf(x0 - x1)));
            const float lp  = ((cl == 1) ? x0 : x1) - lse;
            acc -= lp * invN;
        }
    }

    // ---- block reduction, one atomic per block ----
    #pragma unroll
    for (int off = 32; off; off >>= 1) acc += __shfl_xor(acc, off);
    __shared__ float wsum[4];
    if (lane == 0) wsum[wslot] = acc;
    __syncthreads();
    if (threadIdx.x == 0) {
        atomicAdd(out, wsum[0] + wsum[1] + wsum[2] + wsum[3]);
    }
}

extern "C" void kernel_launch(void* const* d_in, const int* in_sizes, int n_in,
                              void* d_out, int out_size, void* d_ws, size_t ws_size,
                              hipStream_t stream) {
    const float* bbox_p = (const float*)d_in[0];   // (N,15,7,7)
    const float* cls_p  = (const float*)d_in[1];   // (N,2)
    const float* bbox_g = (const float*)d_in[2];   // (N,5,7,7)
    const int*   cls_l  = (const int*)d_in[3];     // (N,)
    float* out = (float*)d_out;
    const int N = in_sizes[3];

    hipLaunchKernelGGL(zero_kernel, dim3(1), dim3(64), 0, stream, out);
    // 2048 blocks x 4 waves = 8192 waves, 8 samples/wave (grid shape held fixed
    // across rounds; only the LDS-vs-register variable changed this round).
    hipLaunchKernelGGL(loss_kernel, dim3(2048), dim3(256), 0, stream,
                       bbox_p, cls_p, bbox_g, cls_l, out, N);
}

// Round 7
// 296.445 us; speedup vs baseline: 1.0178x; 1.0178x over previous
//
#include <hip/hip_runtime.h>
#include <math.h>

// Detector loss: N=65536 samples, G=7 (49 cells), A=3 anchors, C=2 classes.
// bbox_ : (N,15,7,7) predictions, channel 5a+0 = objectness(a), 5a+1..5a+4 = x,y,w,h
// bbox  : (N, 5,7,7) GT,          channel 0 = prob map,        1..4       = x,y,w,h
// cls_  : (N,2) logits; cls : (N,) labels in {1,2}
// out   : scalar fp32
//
// Round-6 (resubmit; prior two benches failed on infra, no signal):
// PAIRED dwordx2 nt loads. R3 (nt + LDS park, scalar dword loads) is the best
// base (~94 us loss); R4 (readlane/reg-resident) regressed via VGPR pressure.
// Remaining theory: 16 scalar (4 B/lane) VMEM instrs/sample is the limiter
// (guide G13 / common-mistake #2: 2-2.5x). A single sample (735 dw) is only
// 4B-aligned, but a sample PAIR (1470 dw = 5880 B) is 8B-aligned -> dwordx2
// loads: 12 pr + 4 gt = 8 VMEM instr/sample (half of R3), half the loop
// iterations. Pair parked in an 8 KB/wave LDS slot; R3's proven compute body
// runs twice (offsets 0/735, 0/245). 32 KB/block -> 5 blocks/CU, 20 waves/CU.

static constexpr int GG   = 49;
static constexpr int PRD  = 15 * GG;   // 735 dwords / pred sample
static constexpr int GTD  = 5  * GG;   // 245 dwords / gt sample
static constexpr int PR2  = 2 * PRD;   // 1470 dwords / pr pair (5880 B, 8B-aligned)
static constexpr int GT2  = 2 * GTD;   // 490 dwords / gt pair  (1960 B, 8B-aligned)
static constexpr int GOF  = 1536;      // gt offset inside a wave's LDS slot
static constexpr int SLOT = 2048;      // floats per wave slot (8 KB)

typedef float __attribute__((ext_vector_type(2))) f32x2;
typedef int   __attribute__((ext_vector_type(2))) i32x2;

__global__ void zero_kernel(float* out) { if (threadIdx.x == 0) out[0] = 0.0f; }

__global__ __launch_bounds__(256, 5) void loss_kernel(
    const float* __restrict__ pr_all,     // bbox_
    const float* __restrict__ cls_logits, // cls_
    const float* __restrict__ gt_all,     // bbox
    const int*   __restrict__ cls_lbl,    // cls
    float* __restrict__ out, int N)
{
    const int lane  = threadIdx.x & 63;
    const int wslot = threadIdx.x >> 6;
    const int wid   = blockIdx.x * (blockDim.x >> 6) + wslot;
    const int nwaves = gridDim.x * (blockDim.x >> 6);
    const float invG   = 1.0f / 7.0f;
    const float invN   = 1.0f / (float)N;
    const float invN49 = 1.0f / ((float)N * 49.0f);

    __shared__ float L[4][SLOT];          // 32 KB/block -> 5 blocks/CU
    float* __restrict__ Lw = L[wslot];    // pair slot: pr at 0, gt at GOF

    float acc = 0.0f;
    const int npairs = N >> 1;

    for (int q = wid; q < npairs; q += nwaves) {
        const float* prp = pr_all + (size_t)q * PR2;
        const float* gtp = gt_all + (size_t)q * GT2;

        // wave-uniform CE inputs for both samples (vectorized, nt)
        const f32x2 la = __builtin_nontemporal_load(
            (const f32x2*)(cls_logits + 4 * (size_t)q));        // n0: x0,x1
        const f32x2 lb = __builtin_nontemporal_load(
            (const f32x2*)(cls_logits + 4 * (size_t)q + 2));    // n1: x0,x1
        const i32x2 ci = __builtin_nontemporal_load(
            (const i32x2*)(cls_lbl + 2 * (size_t)q));           // labels

        // ---- 1) stream the pair: 16 independent coalesced dwordx2 nt loads ----
        f32x2 pv[12];
        #pragma unroll
        for (int k = 0; k < 12; ++k) {
            int d = 2 * lane + 128 * k;
            if (d > PR2 - 2) d = PR2 - 2;          // tail clamp (k=11, lanes>30)
            pv[k] = __builtin_nontemporal_load((const f32x2*)(prp + d));
        }
        f32x2 gv[4];
        #pragma unroll
        for (int k = 0; k < 4; ++k) {
            int d = 2 * lane + 128 * k;
            if (d > GT2 - 2) d = GT2 - 2;          // tail clamp (k=3, lanes>52)
            gv[k] = __builtin_nontemporal_load((const f32x2*)(gtp + d));
        }

        // ---- 2) park pair in this wave's LDS slot (8B ds_writes, no barrier) ----
        #pragma unroll
        for (int k = 0; k < 12; ++k) {
            int d = 2 * lane + 128 * k;
            if (d > PR2 - 2) d = PR2 - 2;          // duplicate writes: same data
            *reinterpret_cast<f32x2*>(&Lw[d]) = pv[k];
        }
        #pragma unroll
        for (int k = 0; k < 4; ++k) {
            int d = 2 * lane + 128 * k;
            if (d > GT2 - 2) d = GT2 - 2;
            *reinterpret_cast<f32x2*>(&Lw[GOF + d]) = gv[k];
        }
        asm volatile("s_waitcnt lgkmcnt(0)" ::: "memory");

        // ---- 3) per-sample compute (R3's proven body), twice per park ----
        #pragma unroll
        for (int s = 0; s < 2; ++s) {
            const float* __restrict__ Lp = Lw + s * PRD;
            const float* __restrict__ Lg = Lw + GOF + s * GTD;
            const float x0 = s ? lb.x : la.x;
            const float x1 = s ? lb.y : la.y;
            const int   cl = s ? ci.y : ci.x;

            // 3a) GT prob argmax: 6 max rounds + ballot (min-index tie-break)
            const int ll = (lane < GG) ? lane : 0;
            const float tv = Lg[ll];
            const float t  = (lane < GG) ? tv : -1.0f;   // sentinel loses (>=0.01)
            float v = t;
            #pragma unroll
            for (int off = 32; off; off >>= 1) v = fmaxf(v, __shfl_xor(v, off));
            const unsigned long long eq = __ballot(t == v);
            const int m  = __ffsll(eq) - 1;              // wave-uniform, [0,49)
            const int mi = m / 7, mj = m - mi * 7;
            const float jf = (float)mj, if_ = (float)mi;

            // 3b) cell-m GT box via uniform LDS broadcast reads
            const float g1v = Lg[ 49 + m];
            const float g2v = Lg[ 98 + m];
            const float g3v = Lg[147 + m];
            const float g4v = Lg[196 + m];

            const float tx  = (g1v + jf) * invG;
            const float ty  = (g2v + if_) * invG;
            const float tx1 = tx - g3v * 0.5f, tx2 = tx + g3v * 0.5f;
            const float ty1 = ty - g4v * 0.5f, ty2 = ty + g4v * 0.5f;
            const float tarea = (tx2 - tx1) * (ty2 - ty1);

            // 3c) IoU argmax over anchors (uniform on all lanes)
            int best = 0; float bestIoU = -1.0f;
            float px = 0.f, py = 0.f, pw = 0.f, ph = 0.f;
            #pragma unroll
            for (int a = 0; a < 3; a++) {
                const float c1 = Lp[(5 * a + 1) * GG + m];
                const float c2 = Lp[(5 * a + 2) * GG + m];
                const float c3 = Lp[(5 * a + 3) * GG + m];
                const float c4 = Lp[(5 * a + 4) * GG + m];
                const float ax  = (c1 + jf) * invG;
                const float ay  = (c2 + if_) * invG;
                const float ax1 = ax - c3 * 0.5f, ax2 = ax + c3 * 0.5f;
                const float ay1 = ay - c4 * 0.5f, ay2 = ay + c4 * 0.5f;
                float iw = fminf(ax2, tx2) - fmaxf(ax1, tx1); iw = fmaxf(iw, 0.0f);
                float ih = fminf(ay2, ty2) - fmaxf(ay1, ty1); ih = fmaxf(ih, 0.0f);
                const float inter = iw * ih;
                const float uni   = (ax2 - ax1) * (ay2 - ay1) + tarea - inter;
                const float iou   = inter / (uni + 1e-9f);
                if (iou > bestIoU) { bestIoU = iou; best = a;
                                     px = c1; py = c2; pw = c3; ph = c4; }
            }

            // 3d) prob_loss: 3x -log(1-p) + best-channel correction (4 trans)
            float sa = 0.0f;
            if (lane < GG) {
                const float p0 = Lp[lane];
                const float p1 = Lp[5 * GG  + lane];
                const float p2 = Lp[10 * GG + lane];
                const float l0 = __logf(1.0f - p0);
                const float l1 = __logf(1.0f - p1);
                const float l2 = __logf(1.0f - p2);
                sa = -(l0 + l1 + l2);
                const float pbv  = (best == 0) ? p0 : (best == 1) ? p1 : p2;
                const float l1pb = (best == 0) ? l0 : (best == 1) ? l1 : l2;
                sa -= t * (__logf(pbv) - l1pb);
            }
            acc += sa * invN49;

            // 3e) coord + size: 8 logs packed into ONE v_log_f32 on lanes 0-7.
            //     lanes: 0:px 1:1-px 2:py 3:1-py 4:pw 5:g3 6:ph 7:g4
            const float s0  = (lane < 4) ? ((lane < 2) ? px : py)
                                         : ((lane < 6) ? pw : ph);
            const float s1  = (lane < 4) ? (1.0f - s0)
                                         : ((lane < 6) ? g3v : g4v);
            const float lav = (lane & 1) ? s1 : s0;      // >0 on every lane
            const float Lv  = __logf(lav);
            const float Lx  = __shfl_xor(Lv, 1);
            float contrib = 0.0f;
            if (lane < 4) {
                const float w = (lane < 2) ? ((lane & 1) ? 1.0f - g1v : g1v)
                                           : ((lane & 1) ? 1.0f - g2v : g2v);
                contrib = -w * Lv;                        // coord BCE terms
            } else if (lane == 4 || lane == 6) {
                contrib = fabsf(Lv - Lx);                 // size log-L1 terms
            }
            acc += contrib;

            // 3f) CE mean on lane 5: lse = mx + log(1 + exp(-|x0-x1|))
            if (lane == 5) {
                const float mx  = fmaxf(x0, x1);
                const float lse = mx + __logf(1.0f + __expf(-fabsf(x0 - x1)));
                const float lp  = ((cl == 1) ? x0 : x1) - lse;
                acc -= lp * invN;
            }
        }
    }

    // ---- block reduction, one atomic per block ----
    #pragma unroll
    for (int off = 32; off; off >>= 1) acc += __shfl_xor(acc, off);
    __shared__ float wsum[4];
    if (lane == 0) wsum[wslot] = acc;
    __syncthreads();
    if (threadIdx.x == 0) {
        atomicAdd(out, wsum[0] + wsum[1] + wsum[2] + wsum[3]);
    }
}

extern "C" void kernel_launch(void* const* d_in, const int* in_sizes, int n_in,
                              void* d_out, int out_size, void* d_ws, size_t ws_size,
                              hipStream_t stream) {
    const float* bbox_p = (const float*)d_in[0];   // (N,15,7,7)
    const float* cls_p  = (const float*)d_in[1];   // (N,2)
    const float* bbox_g = (const float*)d_in[2];   // (N,5,7,7)
    const int*   cls_l  = (const int*)d_in[3];     // (N,)
    float* out = (float*)d_out;
    const int N = in_sizes[3];

    hipLaunchKernelGGL(zero_kernel, dim3(1), dim3(64), 0, stream, out);
    // 2048 blocks x 4 waves = 8192 waves; 32768 pairs -> 4 pairs/wave.
    hipLaunchKernelGGL(loss_kernel, dim3(2048), dim3(256), 0, stream,
                       bbox_p, cls_p, bbox_g, cls_l, out, N);
}